// Round 1
// baseline (18121.402 us; speedup 1.0000x reference)
//
#include <hip/hip_runtime.h>
#include <hip/hip_bf16.h>
#include <cstdint>

#define B_ 32
#define T_ 1024
#define E_ 256
#define H_ 256
#define G_ 1024
#define NTAG 14

typedef __bf16 bf8_t __attribute__((ext_vector_type(8)));
typedef float f4_t __attribute__((ext_vector_type(4)));
typedef unsigned short u16x4 __attribute__((ext_vector_type(4)));

__device__ __forceinline__ unsigned short f2bf(float f) {
    unsigned u = __builtin_bit_cast(unsigned, f);
    u = u + 0x7FFFu + ((u >> 16) & 1u);
    return (unsigned short)(u >> 16);
}
__device__ __forceinline__ float bf2f(unsigned short s) {
    unsigned u = ((unsigned)s) << 16;
    return __builtin_bit_cast(float, u);
}
__device__ __forceinline__ float sigf(float x) { return 1.0f / (1.0f + __expf(-x)); }
__device__ __forceinline__ float tanhf_(float x) {
    float a = fabsf(x);
    float e = __expf(-2.0f * a);
    float r = (1.0f - e) / (1.0f + e);
    return x < 0.0f ? -r : r;
}
__device__ __forceinline__ f4_t mfma16(bf8_t a, bf8_t b, f4_t c) {
    return __builtin_amdgcn_mfma_f32_16x16x32_bf16(a, b, c, 0, 0, 0);
}

// ---------------- prep: convert weights to bf16, combine biases ----------------
__global__ __launch_bounds__(256) void prep_kernel(
        const float* whh_f, const float* whh_b,
        const float* wih_f, const float* wih_b,
        const float* bih_f, const float* bhh_f,
        const float* bih_b, const float* bhh_b,
        const float* wout,
        unsigned short* whh_bf, unsigned short* wih_bf,
        float* biasc, unsigned short* wout_bf) {
    int tid = blockIdx.x * 256 + threadIdx.x;
    if (tid < 524288) {                       // 2 x 262144: [d][1024][256]
        int d = tid >> 18, off = tid & 262143;
        whh_bf[tid] = f2bf((d ? whh_b : whh_f)[off]);
        wih_bf[tid] = f2bf((d ? wih_b : wih_f)[off]);
        return;
    }
    int t2 = tid - 524288;
    if (t2 < 8192) {                          // wout padded [16][512]
        int n = t2 >> 9, k = t2 & 511;
        wout_bf[t2] = (n < NTAG) ? f2bf(wout[n * 512 + k]) : (unsigned short)0;
        return;
    }
    int t3 = t2 - 8192;
    if (t3 < 2048) {                          // biasc [2][1024]
        int d = t3 >> 10, g = t3 & 1023;
        biasc[t3] = d ? (bih_b[g] + bhh_b[g]) : (bih_f[g] + bhh_f[g]);
    }
}

// ---------------- embedding gather -> bf16 ----------------
__global__ __launch_bounds__(256) void embed_kernel(const int* sent, const float* emb,
                                                    unsigned short* xbf) {
    int tid = blockIdx.x * 256 + threadIdx.x; // 32768*64 threads
    int bt = tid >> 6;
    int e0 = (tid & 63) << 2;
    int tok = sent[bt];
    float4 v = *reinterpret_cast<const float4*>(emb + (size_t)tok * E_ + e0);
    u16x4 o;
    o[0] = f2bf(v.x); o[1] = f2bf(v.y); o[2] = f2bf(v.z); o[3] = f2bf(v.w);
    *reinterpret_cast<u16x4*>(xbf + (size_t)bt * E_ + e0) = o;
}

// ---------------- input projection: xg[d][bt][1024] = x @ Wih^T + (bih+bhh) ----------------
__global__ __launch_bounds__(256) void xproj_kernel(const unsigned short* xbf,
        const unsigned short* wih_bf, const float* biasc, unsigned short* xg) {
    int mt = blockIdx.x;                 // 0..2047 (16 tokens each)
    int d = blockIdx.y >> 2;
    int ns = blockIdx.y & 3;             // 256-wide n slice
    int w = threadIdx.x >> 6, l = threadIdx.x & 63;
    int l15 = l & 15, lgp = l >> 4;

    bf8_t a[8];
    const unsigned short* arow = xbf + (size_t)(16 * mt + l15) * E_ + 8 * lgp;
#pragma unroll
    for (int ks = 0; ks < 8; ++ks)
        a[ks] = *reinterpret_cast<const bf8_t*>(arow + 32 * ks);

    int nbase = ns * 256 + w * 64;
    const unsigned short* wd = wih_bf + (size_t)d * 262144;
    f4_t acc[4];
#pragma unroll
    for (int p = 0; p < 4; ++p) { acc[p][0] = 0.f; acc[p][1] = 0.f; acc[p][2] = 0.f; acc[p][3] = 0.f; }
#pragma unroll
    for (int p = 0; p < 4; ++p) {
        int n = nbase + 16 * p + l15;
        const unsigned short* brow = wd + (size_t)n * E_ + 8 * lgp;
#pragma unroll
        for (int ks = 0; ks < 8; ++ks) {
            bf8_t b = *reinterpret_cast<const bf8_t*>(brow + 32 * ks);
            acc[p] = mfma16(a[ks], b, acc[p]);
        }
    }
#pragma unroll
    for (int p = 0; p < 4; ++p) {
        int n = nbase + 16 * p + l15;
        float bias = biasc[d * G_ + n];
#pragma unroll
        for (int r = 0; r < 4; ++r) {
            int bt = 16 * mt + 4 * lgp + r;
            xg[((size_t)d * 32768 + bt) * G_ + n] = f2bf(acc[p][r] + bias);
        }
    }
}

// ---------------- recurrence: 4 WGs = (dir, half-batch of 16), M=16 MFMA ----------------
__global__ __launch_bounds__(512) void lstm_kernel(const unsigned short* xg,
        const unsigned short* whh_bf, const float* h0, const float* c0,
        unsigned short* hs) {
    int d = blockIdx.x & 1, half = blockIdx.x >> 1;
    int b0 = half * 16;
    int tid = threadIdx.x;
    int w = tid >> 6, l = tid & 63, l15 = l & 15, lgp = l >> 4;

    __shared__ unsigned short h_sh[2][16][264];   // +8 pad breaks bank conflicts

    for (int e = tid; e < 16 * 256; e += 512) {
        int m = e >> 8, col = e & 255;
        h_sh[0][m][col] = f2bf(h0[((size_t)d * 32 + b0 + m) * 256 + col]);
    }
    float c[2][4];
#pragma unroll
    for (int p = 0; p < 2; ++p)
#pragma unroll
        for (int r = 0; r < 4; ++r)
            c[p][r] = c0[((size_t)d * 32 + b0 + 4 * lgp + r) * 256 + 16 * (2 * w + p) + l15];

    const unsigned short* wd = whh_bf + (size_t)d * 262144;
    const unsigned short* xgd = xg + (size_t)d * 32768 * 1024;
    __syncthreads();

    for (int s = 0; s < 1024; ++s) {
        int t = d ? (1023 - s) : s;
        int cur = s & 1, nxt = cur ^ 1;

        f4_t acc[4][2];
#pragma unroll
        for (int gt = 0; gt < 4; ++gt)
#pragma unroll
            for (int p = 0; p < 2; ++p)
#pragma unroll
                for (int r = 0; r < 4; ++r) {
                    int n = 256 * gt + 16 * (2 * w + p) + l15;
                    int bt = (b0 + 4 * lgp + r) * 1024 + t;
                    acc[gt][p][r] = bf2f(xgd[(size_t)bt * 1024 + n]);
                }

        bf8_t a[8];
#pragma unroll
        for (int ks = 0; ks < 8; ++ks)
            a[ks] = *reinterpret_cast<const bf8_t*>(&h_sh[cur][l15][32 * ks + 8 * lgp]);

#pragma unroll
        for (int gt = 0; gt < 4; ++gt)
#pragma unroll
            for (int p = 0; p < 2; ++p) {
                int nt = 2 * w + p + 16 * gt;
                const unsigned short* brow = wd + (size_t)(16 * nt + l15) * 256 + 8 * lgp;
#pragma unroll
                for (int ks = 0; ks < 8; ++ks) {
                    bf8_t b = *reinterpret_cast<const bf8_t*>(brow + 32 * ks);
                    acc[gt][p] = mfma16(a[ks], b, acc[gt][p]);
                }
            }

#pragma unroll
        for (int p = 0; p < 2; ++p)
#pragma unroll
            for (int r = 0; r < 4; ++r) {
                float iv = sigf(acc[0][p][r]);
                float fv = sigf(acc[1][p][r]);
                float gv = tanhf_(acc[2][p][r]);
                float ov = sigf(acc[3][p][r]);
                float cn = fv * c[p][r] + iv * gv;
                c[p][r] = cn;
                float hv = ov * tanhf_(cn);
                unsigned short hb = f2bf(hv);
                int m = 4 * lgp + r, j = 16 * (2 * w + p) + l15;
                h_sh[nxt][m][j] = hb;
                hs[((size_t)(b0 + m) * 1024 + t) * 512 + d * 256 + j] = hb;
            }
        __syncthreads();
    }
}

// ---------------- logits = hs @ Wout^T + b_out (N padded to 16) ----------------
__global__ __launch_bounds__(256) void logits_kernel(const unsigned short* hs,
        const unsigned short* wout_bf, const float* b_out, float* logits) {
    int w = threadIdx.x >> 6, l = threadIdx.x & 63, l15 = l & 15, lgp = l >> 4;
    int mt = blockIdx.x * 4 + w;         // 0..2047
    const unsigned short* arow = hs + (size_t)(16 * mt + l15) * 512 + 8 * lgp;
    const unsigned short* brow = wout_bf + (size_t)l15 * 512 + 8 * lgp;
    f4_t acc; acc[0] = 0.f; acc[1] = 0.f; acc[2] = 0.f; acc[3] = 0.f;
#pragma unroll
    for (int ks = 0; ks < 16; ++ks) {
        bf8_t a = *reinterpret_cast<const bf8_t*>(arow + 32 * ks);
        bf8_t b = *reinterpret_cast<const bf8_t*>(brow + 32 * ks);
        acc = mfma16(a, b, acc);
    }
    float bo = (l15 < NTAG) ? b_out[l15] : 0.0f;
#pragma unroll
    for (int r = 0; r < 4; ++r) {
        int bt = 16 * mt + 4 * lgp + r;
        logits[(size_t)bt * 16 + l15] = acc[r] + bo;
    }
}

// ---------------- Viterbi: one wave per sequence ----------------
__global__ __launch_bounds__(64) void viterbi_kernel(const float* logits, const float* crf,
                                                     float* out) {
    int b = blockIdx.x, j = threadIdx.x;
    __shared__ unsigned char bp[1024][16];
    __shared__ unsigned char pth[1024];
    float crfj[NTAG];
#pragma unroll
    for (int i = 0; i < NTAG; ++i)
        crfj[i] = (j < NTAG) ? crf[i * NTAG + j] : 0.0f;
    const float* lgt = logits + (size_t)b * 1024 * 16;
    float v = (j < NTAG) ? lgt[j] : -3.0e38f;
    for (int t = 1; t < 1024; ++t) {
        float lt = (j < NTAG) ? lgt[t * 16 + j] : 0.0f;
        float best = -3.0e38f; int arg = 0;
#pragma unroll
        for (int i = 0; i < NTAG; ++i) {
            float s = __shfl(v, i) + crfj[i];
            if (s > best) { best = s; arg = i; }   // strict > keeps lowest index (jnp.argmax)
        }
        v = (j < NTAG) ? (lt + best) : -3.0e38f;
        if (j < 16) bp[t][j] = (unsigned char)arg;
    }
    // final max over tags (all lanes compute the same result)
    float best = -3.0e38f; int tag = 0;
#pragma unroll
    for (int jj = 0; jj < NTAG; ++jj) {
        float s = __shfl(v, jj);
        if (s > best) { best = s; tag = jj; }
    }
    __syncthreads();
    if (j == 0) {
        out[b] = best;
        int tg = tag;
        pth[1023] = (unsigned char)tg;
        for (int t = 1023; t >= 1; --t) {
            tg = bp[t][tg];
            pth[t - 1] = (unsigned char)tg;
        }
    }
    __syncthreads();
    float* pout = out + 32 + (size_t)b * 1024;
    for (int t = j; t < 1024; t += 64)
        pout[t] = (float)pth[t];
}

extern "C" void kernel_launch(void* const* d_in, const int* in_sizes, int n_in,
                              void* d_out, int out_size, void* d_ws, size_t ws_size,
                              hipStream_t stream) {
    const int* sent = (const int*)d_in[0];
    const float* emb = (const float*)d_in[1];
    const float* wih_f = (const float*)d_in[2];
    const float* whh_f = (const float*)d_in[3];
    const float* bih_f = (const float*)d_in[4];
    const float* bhh_f = (const float*)d_in[5];
    const float* wih_b = (const float*)d_in[6];
    const float* whh_b = (const float*)d_in[7];
    const float* bih_b = (const float*)d_in[8];
    const float* bhh_b = (const float*)d_in[9];
    const float* h0 = (const float*)d_in[10];
    const float* c0 = (const float*)d_in[11];
    const float* wout = (const float*)d_in[12];
    const float* b_out = (const float*)d_in[13];
    const float* crf = (const float*)d_in[14];

    char* ws = (char*)d_ws;
    unsigned short* whh_bf = (unsigned short*)(ws + 0);           // 1 MiB
    unsigned short* wih_bf = (unsigned short*)(ws + 1048576);     // 1 MiB
    float* biasc          = (float*)(ws + 2097152);               // 8 KiB
    unsigned short* wout_bf = (unsigned short*)(ws + 2105344);    // 16 KiB
    unsigned short* xbf   = (unsigned short*)(ws + 2121728);      // 16 MiB
    unsigned short* xg    = (unsigned short*)(ws + 18898944);     // 128 MiB
    unsigned short* hs    = (unsigned short*)(ws + 153116672);    // 32 MiB
    float* logits         = (float*)(ws + 186671104);             // 2 MiB
    float* out = (float*)d_out;

    hipLaunchKernelGGL(prep_kernel, dim3(2088), dim3(256), 0, stream,
                       whh_f, whh_b, wih_f, wih_b, bih_f, bhh_f, bih_b, bhh_b, wout,
                       whh_bf, wih_bf, biasc, wout_bf);
    hipLaunchKernelGGL(embed_kernel, dim3(8192), dim3(256), 0, stream, sent, emb, xbf);
    hipLaunchKernelGGL(xproj_kernel, dim3(2048, 8), dim3(256), 0, stream,
                       xbf, wih_bf, biasc, xg);
    hipLaunchKernelGGL(lstm_kernel, dim3(4), dim3(512), 0, stream, xg, whh_bf, h0, c0, hs);
    hipLaunchKernelGGL(logits_kernel, dim3(512), dim3(256), 0, stream,
                       hs, wout_bf, b_out, logits);
    hipLaunchKernelGGL(viterbi_kernel, dim3(32), dim3(64), 0, stream, logits, crf, out);
}

// Round 2
// 7544.510 us; speedup vs baseline: 2.4019x; 2.4019x over previous
//
#include <hip/hip_runtime.h>
#include <hip/hip_bf16.h>
#include <cstdint>

#define B_ 32
#define T_ 1024
#define E_ 256
#define H_ 256
#define G_ 1024
#define NTAG 14

typedef __bf16 bf8_t __attribute__((ext_vector_type(8)));
typedef float f4_t __attribute__((ext_vector_type(4)));
typedef unsigned short u16x4 __attribute__((ext_vector_type(4)));

__device__ __forceinline__ unsigned short f2bf(float f) {
    unsigned u = __builtin_bit_cast(unsigned, f);
    u = u + 0x7FFFu + ((u >> 16) & 1u);
    return (unsigned short)(u >> 16);
}
__device__ __forceinline__ float bf2f(unsigned short s) {
    unsigned u = ((unsigned)s) << 16;
    return __builtin_bit_cast(float, u);
}
__device__ __forceinline__ float sigf(float x) { return 1.0f / (1.0f + __expf(-x)); }
__device__ __forceinline__ float tanhf_(float x) {
    float a = fabsf(x);
    float e = __expf(-2.0f * a);
    float r = (1.0f - e) / (1.0f + e);
    return x < 0.0f ? -r : r;
}
__device__ __forceinline__ f4_t mfma16(bf8_t a, bf8_t b, f4_t c) {
    return __builtin_amdgcn_mfma_f32_16x16x32_bf16(a, b, c, 0, 0, 0);
}

// ---------------- prep: convert weights to bf16, combine biases, zero flags ----------------
__global__ __launch_bounds__(256) void prep_kernel(
        const float* whh_f, const float* whh_b,
        const float* wih_f, const float* wih_b,
        const float* bih_f, const float* bhh_f,
        const float* bih_b, const float* bhh_b,
        const float* wout,
        unsigned short* whh_bf, unsigned short* wih_bf,
        float* biasc, unsigned short* wout_bf, unsigned int* flags) {
    int tid = blockIdx.x * 256 + threadIdx.x;
    if (tid < 524288) {                       // 2 x 262144: [d][1024][256]
        int d = tid >> 18, off = tid & 262143;
        whh_bf[tid] = f2bf((d ? whh_b : whh_f)[off]);
        wih_bf[tid] = f2bf((d ? wih_b : wih_f)[off]);
        return;
    }
    int t2 = tid - 524288;
    if (t2 < 8192) {                          // wout padded [16][512]
        int n = t2 >> 9, k = t2 & 511;
        wout_bf[t2] = (n < NTAG) ? f2bf(wout[n * 512 + k]) : (unsigned short)0;
        return;
    }
    int t3 = t2 - 8192;
    if (t3 < 2048) {                          // biasc [2][1024]
        int d = t3 >> 10, g = t3 & 1023;
        biasc[t3] = d ? (bih_b[g] + bhh_b[g]) : (bih_f[g] + bhh_f[g]);
        return;
    }
    int t4 = t3 - 2048;
    if (t4 < 8) flags[t4] = 0;                // per-WG step flags
}

// ---------------- embedding gather -> bf16 ----------------
__global__ __launch_bounds__(256) void embed_kernel(const int* sent, const float* emb,
                                                    unsigned short* xbf) {
    int tid = blockIdx.x * 256 + threadIdx.x; // 32768*64 threads
    int bt = tid >> 6;
    int e0 = (tid & 63) << 2;
    int tok = sent[bt];
    float4 v = *reinterpret_cast<const float4*>(emb + (size_t)tok * E_ + e0);
    u16x4 o;
    o[0] = f2bf(v.x); o[1] = f2bf(v.y); o[2] = f2bf(v.z); o[3] = f2bf(v.w);
    *reinterpret_cast<u16x4*>(xbf + (size_t)bt * E_ + e0) = o;
}

// ---------------- input projection: xg[d][bt][1024] = x @ Wih^T + (bih+bhh) ----------------
__global__ __launch_bounds__(256) void xproj_kernel(const unsigned short* xbf,
        const unsigned short* wih_bf, const float* biasc, unsigned short* xg) {
    int mt = blockIdx.x;                 // 0..2047 (16 tokens each)
    int d = blockIdx.y >> 2;
    int ns = blockIdx.y & 3;             // 256-wide n slice
    int w = threadIdx.x >> 6, l = threadIdx.x & 63;
    int l15 = l & 15, lgp = l >> 4;

    bf8_t a[8];
    const unsigned short* arow = xbf + (size_t)(16 * mt + l15) * E_ + 8 * lgp;
#pragma unroll
    for (int ks = 0; ks < 8; ++ks)
        a[ks] = *reinterpret_cast<const bf8_t*>(arow + 32 * ks);

    int nbase = ns * 256 + w * 64;
    const unsigned short* wd = wih_bf + (size_t)d * 262144;
    f4_t acc[4];
#pragma unroll
    for (int p = 0; p < 4; ++p) { acc[p][0] = 0.f; acc[p][1] = 0.f; acc[p][2] = 0.f; acc[p][3] = 0.f; }
#pragma unroll
    for (int p = 0; p < 4; ++p) {
        int n = nbase + 16 * p + l15;
        const unsigned short* brow = wd + (size_t)n * E_ + 8 * lgp;
#pragma unroll
        for (int ks = 0; ks < 8; ++ks) {
            bf8_t b = *reinterpret_cast<const bf8_t*>(brow + 32 * ks);
            acc[p] = mfma16(a[ks], b, acc[p]);
        }
    }
#pragma unroll
    for (int p = 0; p < 4; ++p) {
        int n = nbase + 16 * p + l15;
        float bias = biasc[d * G_ + n];
#pragma unroll
        for (int r = 0; r < 4; ++r) {
            int bt = 16 * mt + 4 * lgp + r;
            xg[((size_t)d * 32768 + bt) * G_ + n] = f2bf(acc[p][r] + bias);
        }
    }
}

// ---------------- recurrence: 8 WGs = (dir, batch-16, N-half-512), weights in registers ----
// WG pair (d,b,{0,1}) exchanges h halves each step via agent-scope atomics.
__global__ __launch_bounds__(512, 2) void lstm_kernel(const unsigned short* xg,
        const unsigned short* whh_bf, const float* h0, const float* c0,
        unsigned short* hs, unsigned long long* pub, unsigned int* flags) {
    int bid = blockIdx.x;
    int nh = bid & 1, b = (bid >> 1) & 1, d = bid >> 2;
    int tid = threadIdx.x;
    int w = tid >> 6, l = tid & 63, l15 = l & 15, lgp = l >> 4;
    int jg = 128 * nh + 16 * w + l15;     // this lane's hidden column j (global 0..255)

    __shared__ unsigned short h_sh[2][16][264];   // parity x [batch-row 16] x [256 + pad]

    // ---- resident weights: 4 gate-tiles x 8 k-steps = 128 VGPRs of bf16 ----
    const unsigned short* wd = whh_bf + (size_t)d * 262144;
    bf8_t wreg[4][8];
#pragma unroll
    for (int gt = 0; gt < 4; ++gt) {
        int row = 256 * gt + 128 * nh + 16 * w + l15;
        const unsigned short* brow = wd + (size_t)row * 256 + 8 * lgp;
#pragma unroll
        for (int ks = 0; ks < 8; ++ks)
            wreg[gt][ks] = *reinterpret_cast<const bf8_t*>(brow + 32 * ks);
    }

    // ---- c init (4 batch rows per lane at column jg) ----
    float c[4];
#pragma unroll
    for (int r = 0; r < 4; ++r)
        c[r] = c0[((size_t)d * 32 + 16 * b + 4 * lgp + r) * 256 + jg];

    // ---- h(-1) = h0 staged full-width into parity-1 buffer ----
    for (int e = tid; e < 16 * 256; e += 512) {
        int m = e >> 8, col = e & 255;
        h_sh[1][m][col] = f2bf(h0[((size_t)d * 32 + 16 * b + m) * 256 + col]);
    }

    const unsigned short* xgd = xg + (size_t)d * 32768 * 1024;
    size_t wgid = (size_t)(d * 2 + b) * 2 + nh;
    size_t pgid = (size_t)(d * 2 + b) * 2 + (1 - nh);
    unsigned long long* mypub = pub + wgid * 1024;      // [parity][512] u64
    unsigned long long* ppub = pub + pgid * 1024;
    unsigned int* myflag = flags + wgid;
    unsigned int* pflag = flags + pgid;
    int prow = tid >> 5, pc4 = (tid & 31) * 4;          // publish/stage coords

    __syncthreads();

    for (int s = 0; s < 1024; ++s) {
        int t = d ? (1023 - s) : s;
        int rp = (s + 1) & 1;     // parity holding h(s-1)
        int wp = s & 1;           // parity to write h(s)

        // xg pre-activation values for this step (independent of h -> issued early)
        unsigned short xv[16];
#pragma unroll
        for (int gt = 0; gt < 4; ++gt)
#pragma unroll
            for (int r = 0; r < 4; ++r) {
                int row = 16 * b + 4 * lgp + r;
                xv[gt * 4 + r] = xgd[((size_t)row * 1024 + t) * 1024 + 256 * gt + jg];
            }

        // A fragments: full h(s-1)
        bf8_t a[8];
#pragma unroll
        for (int ks = 0; ks < 8; ++ks)
            a[ks] = *reinterpret_cast<const bf8_t*>(&h_sh[rp][l15][32 * ks + 8 * lgp]);

        f4_t acc[4];
#pragma unroll
        for (int gt = 0; gt < 4; ++gt) { acc[gt][0] = 0.f; acc[gt][1] = 0.f; acc[gt][2] = 0.f; acc[gt][3] = 0.f; }
#pragma unroll
        for (int gt = 0; gt < 4; ++gt)
#pragma unroll
            for (int ks = 0; ks < 8; ++ks)
                acc[gt] = mfma16(a[ks], wreg[gt][ks], acc[gt]);

        // gates + state update; write own h columns
#pragma unroll
        for (int r = 0; r < 4; ++r) {
            float iv = sigf(acc[0][r] + bf2f(xv[0 + r]));
            float fv = sigf(acc[1][r] + bf2f(xv[4 + r]));
            float gv = tanhf_(acc[2][r] + bf2f(xv[8 + r]));
            float ov = sigf(acc[3][r] + bf2f(xv[12 + r]));
            float cn = fv * c[r] + iv * gv;
            c[r] = cn;
            unsigned short hb = f2bf(ov * tanhf_(cn));
            int m = 4 * lgp + r;
            h_sh[wp][m][jg] = hb;
            hs[((size_t)(16 * b + m) * 1024 + t) * 512 + d * 256 + jg] = hb;
        }
        __syncthreads();   // B1: own half of h_sh[wp] complete

        // publish own half (coalesced u64, agent scope so partner XCD sees it)
        {
            unsigned long long pv =
                *reinterpret_cast<const unsigned long long*>(&h_sh[wp][prow][128 * nh + pc4]);
            __hip_atomic_store(&mypub[(size_t)wp * 512 + tid], pv,
                               __ATOMIC_RELAXED, __HIP_MEMORY_SCOPE_AGENT);
        }
        __threadfence();
        __syncthreads();   // B2: all publish stores fenced
        if (tid == 0)
            __hip_atomic_store(myflag, (unsigned)(s + 1),
                               __ATOMIC_RELEASE, __HIP_MEMORY_SCOPE_AGENT);
        if (s == 1023) break;

        // wait for partner's h(s), stage into partner half of h_sh[wp]
        while (__hip_atomic_load(pflag, __ATOMIC_ACQUIRE, __HIP_MEMORY_SCOPE_AGENT)
               < (unsigned)(s + 1)) { }
        {
            unsigned long long qv = __hip_atomic_load(&ppub[(size_t)wp * 512 + tid],
                                                      __ATOMIC_RELAXED, __HIP_MEMORY_SCOPE_AGENT);
            *reinterpret_cast<unsigned long long*>(&h_sh[wp][prow][128 * (1 - nh) + pc4]) = qv;
        }
        __syncthreads();   // B3: h_sh[wp] fully assembled for step s+1
    }
}

// ---------------- logits = hs @ Wout^T + b_out (N padded to 16) ----------------
__global__ __launch_bounds__(256) void logits_kernel(const unsigned short* hs,
        const unsigned short* wout_bf, const float* b_out, float* logits) {
    int w = threadIdx.x >> 6, l = threadIdx.x & 63, l15 = l & 15, lgp = l >> 4;
    int mt = blockIdx.x * 4 + w;         // 0..2047
    const unsigned short* arow = hs + (size_t)(16 * mt + l15) * 512 + 8 * lgp;
    const unsigned short* brow = wout_bf + (size_t)l15 * 512 + 8 * lgp;
    f4_t acc; acc[0] = 0.f; acc[1] = 0.f; acc[2] = 0.f; acc[3] = 0.f;
#pragma unroll
    for (int ks = 0; ks < 16; ++ks) {
        bf8_t a = *reinterpret_cast<const bf8_t*>(arow + 32 * ks);
        bf8_t b = *reinterpret_cast<const bf8_t*>(brow + 32 * ks);
        acc = mfma16(a, b, acc);
    }
    float bo = (l15 < NTAG) ? b_out[l15] : 0.0f;
#pragma unroll
    for (int r = 0; r < 4; ++r) {
        int bt = 16 * mt + 4 * lgp + r;
        logits[(size_t)bt * 16 + l15] = acc[r] + bo;
    }
}

// ---------------- Viterbi: one wave per sequence ----------------
__global__ __launch_bounds__(64) void viterbi_kernel(const float* logits, const float* crf,
                                                     float* out) {
    int b = blockIdx.x, j = threadIdx.x;
    __shared__ unsigned char bp[1024][16];
    __shared__ unsigned char pth[1024];
    float crfj[NTAG];
#pragma unroll
    for (int i = 0; i < NTAG; ++i)
        crfj[i] = (j < NTAG) ? crf[i * NTAG + j] : 0.0f;
    const float* lgt = logits + (size_t)b * 1024 * 16;
    float v = (j < NTAG) ? lgt[j] : -3.0e38f;
    for (int t = 1; t < 1024; ++t) {
        float lt = (j < NTAG) ? lgt[t * 16 + j] : 0.0f;
        float best = -3.0e38f; int arg = 0;
#pragma unroll
        for (int i = 0; i < NTAG; ++i) {
            float s = __shfl(v, i) + crfj[i];
            if (s > best) { best = s; arg = i; }   // strict > keeps lowest index (jnp.argmax)
        }
        v = (j < NTAG) ? (lt + best) : -3.0e38f;
        if (j < 16) bp[t][j] = (unsigned char)arg;
    }
    float best = -3.0e38f; int tag = 0;
#pragma unroll
    for (int jj = 0; jj < NTAG; ++jj) {
        float s = __shfl(v, jj);
        if (s > best) { best = s; tag = jj; }
    }
    __syncthreads();
    if (j == 0) {
        out[b] = best;
        int tg = tag;
        pth[1023] = (unsigned char)tg;
        for (int t = 1023; t >= 1; --t) {
            tg = bp[t][tg];
            pth[t - 1] = (unsigned char)tg;
        }
    }
    __syncthreads();
    float* pout = out + 32 + (size_t)b * 1024;
    for (int t = j; t < 1024; t += 64)
        pout[t] = (float)pth[t];
}

extern "C" void kernel_launch(void* const* d_in, const int* in_sizes, int n_in,
                              void* d_out, int out_size, void* d_ws, size_t ws_size,
                              hipStream_t stream) {
    const int* sent = (const int*)d_in[0];
    const float* emb = (const float*)d_in[1];
    const float* wih_f = (const float*)d_in[2];
    const float* whh_f = (const float*)d_in[3];
    const float* bih_f = (const float*)d_in[4];
    const float* bhh_f = (const float*)d_in[5];
    const float* wih_b = (const float*)d_in[6];
    const float* whh_b = (const float*)d_in[7];
    const float* bih_b = (const float*)d_in[8];
    const float* bhh_b = (const float*)d_in[9];
    const float* h0 = (const float*)d_in[10];
    const float* c0 = (const float*)d_in[11];
    const float* wout = (const float*)d_in[12];
    const float* b_out = (const float*)d_in[13];
    const float* crf = (const float*)d_in[14];

    char* ws = (char*)d_ws;
    unsigned short* whh_bf = (unsigned short*)(ws + 0);           // 1 MiB
    unsigned short* wih_bf = (unsigned short*)(ws + 1048576);     // 1 MiB
    float* biasc          = (float*)(ws + 2097152);               // 8 KiB
    unsigned short* wout_bf = (unsigned short*)(ws + 2105344);    // 16 KiB
    unsigned short* xbf   = (unsigned short*)(ws + 2121728);      // 16 MiB
    unsigned short* xg    = (unsigned short*)(ws + 18898944);     // 128 MiB
    unsigned short* hs    = (unsigned short*)(ws + 153116672);    // 32 MiB
    float* logits         = (float*)(ws + 186671104);             // 2 MiB
    // pub/flags alias the logits region (dead until logits_kernel, which runs after lstm)
    unsigned long long* pub = (unsigned long long*)(ws + 186671104);   // 64 KiB
    unsigned int* flags     = (unsigned int*)(ws + 186671104 + 65536); // 32 B
    float* out = (float*)d_out;

    hipLaunchKernelGGL(prep_kernel, dim3(2089), dim3(256), 0, stream,
                       whh_f, whh_b, wih_f, wih_b, bih_f, bhh_f, bih_b, bhh_b, wout,
                       whh_bf, wih_bf, biasc, wout_bf, flags);
    hipLaunchKernelGGL(embed_kernel, dim3(8192), dim3(256), 0, stream, sent, emb, xbf);
    hipLaunchKernelGGL(xproj_kernel, dim3(2048, 8), dim3(256), 0, stream,
                       xbf, wih_bf, biasc, xg);
    hipLaunchKernelGGL(lstm_kernel, dim3(8), dim3(512), 0, stream,
                       xg, whh_bf, h0, c0, hs, pub, flags);
    hipLaunchKernelGGL(logits_kernel, dim3(512), dim3(256), 0, stream,
                       hs, wout_bf, b_out, logits);
    hipLaunchKernelGGL(viterbi_kernel, dim3(32), dim3(64), 0, stream, logits, crf, out);
}

// Round 3
// 3811.962 us; speedup vs baseline: 4.7538x; 1.9792x over previous
//
#include <hip/hip_runtime.h>
#include <hip/hip_bf16.h>
#include <cstdint>

#define B_ 32
#define T_ 1024
#define E_ 256
#define H_ 256
#define G_ 1024
#define NTAG 14

typedef __bf16 bf8_t __attribute__((ext_vector_type(8)));
typedef float f4_t __attribute__((ext_vector_type(4)));
typedef unsigned short u16x4 __attribute__((ext_vector_type(4)));

__device__ __forceinline__ unsigned short f2bf(float f) {
    unsigned u = __builtin_bit_cast(unsigned, f);
    u = u + 0x7FFFu + ((u >> 16) & 1u);
    return (unsigned short)(u >> 16);
}
__device__ __forceinline__ float bf2f(unsigned short s) {
    unsigned u = ((unsigned)s) << 16;
    return __builtin_bit_cast(float, u);
}
__device__ __forceinline__ float sigf(float x) { return 1.0f / (1.0f + __expf(-x)); }
__device__ __forceinline__ float tanhf_(float x) {
    float a = fabsf(x);
    float e = __expf(-2.0f * a);
    float r = (1.0f - e) / (1.0f + e);
    return x < 0.0f ? -r : r;
}
__device__ __forceinline__ f4_t mfma16(bf8_t a, bf8_t b, f4_t c) {
    return __builtin_amdgcn_mfma_f32_16x16x32_bf16(a, b, c, 0, 0, 0);
}

// ---------------- prep: convert weights to bf16, combine biases, zero pub tags ----------------
__global__ __launch_bounds__(256) void prep_kernel(
        const float* whh_f, const float* whh_b,
        const float* wih_f, const float* wih_b,
        const float* bih_f, const float* bhh_f,
        const float* bih_b, const float* bhh_b,
        const float* wout,
        unsigned short* whh_bf, unsigned short* wih_bf,
        float* biasc, unsigned short* wout_bf, unsigned int* pubz) {
    int tid = blockIdx.x * 256 + threadIdx.x;
    if (tid < 524288) {                       // 2 x 262144: [d][1024][256]
        int d = tid >> 18, off = tid & 262143;
        whh_bf[tid] = f2bf((d ? whh_b : whh_f)[off]);
        wih_bf[tid] = f2bf((d ? wih_b : wih_f)[off]);
        return;
    }
    int t2 = tid - 524288;
    if (t2 < 8192) {                          // wout padded [16][512]
        int n = t2 >> 9, k = t2 & 511;
        wout_bf[t2] = (n < NTAG) ? f2bf(wout[n * 512 + k]) : (unsigned short)0;
        return;
    }
    int t3 = t2 - 8192;
    if (t3 < 2048) {                          // biasc [2][1024]
        int d = t3 >> 10, g = t3 & 1023;
        biasc[t3] = d ? (bih_b[g] + bhh_b[g]) : (bih_f[g] + bhh_f[g]);
        return;
    }
    int t4 = t3 - 2048;
    if (t4 < 16384) pubz[t4] = 0;             // 64 KiB pub region (tags must start at 0)
}

// ---------------- embedding gather -> bf16 ----------------
__global__ __launch_bounds__(256) void embed_kernel(const int* sent, const float* emb,
                                                    unsigned short* xbf) {
    int tid = blockIdx.x * 256 + threadIdx.x; // 32768*64 threads
    int bt = tid >> 6;
    int e0 = (tid & 63) << 2;
    int tok = sent[bt];
    float4 v = *reinterpret_cast<const float4*>(emb + (size_t)tok * E_ + e0);
    u16x4 o;
    o[0] = f2bf(v.x); o[1] = f2bf(v.y); o[2] = f2bf(v.z); o[3] = f2bf(v.w);
    *reinterpret_cast<u16x4*>(xbf + (size_t)bt * E_ + e0) = o;
}

// ---------------- input projection: xg[d][bt][1024] = x @ Wih^T + (bih+bhh) ----------------
__global__ __launch_bounds__(256) void xproj_kernel(const unsigned short* xbf,
        const unsigned short* wih_bf, const float* biasc, unsigned short* xg) {
    int mt = blockIdx.x;                 // 0..2047 (16 tokens each)
    int d = blockIdx.y >> 2;
    int ns = blockIdx.y & 3;             // 256-wide n slice
    int w = threadIdx.x >> 6, l = threadIdx.x & 63;
    int l15 = l & 15, lgp = l >> 4;

    bf8_t a[8];
    const unsigned short* arow = xbf + (size_t)(16 * mt + l15) * E_ + 8 * lgp;
#pragma unroll
    for (int ks = 0; ks < 8; ++ks)
        a[ks] = *reinterpret_cast<const bf8_t*>(arow + 32 * ks);

    int nbase = ns * 256 + w * 64;
    const unsigned short* wd = wih_bf + (size_t)d * 262144;
    f4_t acc[4];
#pragma unroll
    for (int p = 0; p < 4; ++p) { acc[p][0] = 0.f; acc[p][1] = 0.f; acc[p][2] = 0.f; acc[p][3] = 0.f; }
#pragma unroll
    for (int p = 0; p < 4; ++p) {
        int n = nbase + 16 * p + l15;
        const unsigned short* brow = wd + (size_t)n * E_ + 8 * lgp;
#pragma unroll
        for (int ks = 0; ks < 8; ++ks) {
            bf8_t b = *reinterpret_cast<const bf8_t*>(brow + 32 * ks);
            acc[p] = mfma16(a[ks], b, acc[p]);
        }
    }
#pragma unroll
    for (int p = 0; p < 4; ++p) {
        int n = nbase + 16 * p + l15;
        float bias = biasc[d * G_ + n];
#pragma unroll
        for (int r = 0; r < 4; ++r) {
            int bt = 16 * mt + 4 * lgp + r;
            xg[((size_t)d * 32768 + bt) * G_ + n] = f2bf(acc[p][r] + bias);
        }
    }
}

// ---------------- recurrence: 8 WGs = (dir, batch-16, N-half-512), weights pinned in regs ----
// Pair (d,b,{0,1}) exchanges h halves each step via tagged u64 one-way publish.
__global__ __launch_bounds__(512, 2) void lstm_kernel(const unsigned short* xg,
        const unsigned short* whh_bf, const float* h0, const float* c0,
        unsigned short* hs, unsigned long long* pub) {
    int bid = blockIdx.x;
    int nh = bid & 1, b = (bid >> 1) & 1, d = bid >> 2;
    int tid = threadIdx.x;
    int w = tid >> 6, l = tid & 63, l15 = l & 15, lgp = l >> 4;
    int jg = 128 * nh + 16 * w + l15;     // this lane's hidden column j (global 0..255)

    __shared__ unsigned short h_sh[2][16][264];   // parity x [batch-row 16] x [256 + pad]

    // ---- resident weights: 4 gate-tiles x 8 k-steps = 128 VGPRs of bf16 ----
    const unsigned short* wd = whh_bf + (size_t)d * 262144;
    bf8_t wreg[4][8];
#pragma unroll
    for (int gt = 0; gt < 4; ++gt) {
        int row = 256 * gt + 128 * nh + 16 * w + l15;
        const unsigned short* brow = wd + (size_t)row * 256 + 8 * lgp;
#pragma unroll
        for (int ks = 0; ks < 8; ++ks)
            wreg[gt][ks] = *reinterpret_cast<const bf8_t*>(brow + 32 * ks);
    }
    // pin: volatile asm is the producer of the loop-used values -> loads can't be re-sunk
#pragma unroll
    for (int gt = 0; gt < 4; ++gt)
#pragma unroll
        for (int ks = 0; ks < 8; ++ks)
            asm volatile("" : "+v"(wreg[gt][ks]));

    // ---- c init (4 batch rows per lane at column jg) ----
    float c[4];
#pragma unroll
    for (int r = 0; r < 4; ++r)
        c[r] = c0[((size_t)d * 32 + 16 * b + 4 * lgp + r) * 256 + jg];

    // ---- h(-1) = h0 staged full-width into parity-1 buffer ----
    for (int e = tid; e < 16 * 256; e += 512) {
        int m = e >> 8, col = e & 255;
        h_sh[1][m][col] = f2bf(h0[((size_t)d * 32 + 16 * b + m) * 256 + col]);
    }

    const unsigned short* xgd = xg + (size_t)d * 32768 * 1024;
    int pid = d * 2 + b;
    unsigned long long* mypub = pub + (size_t)(pid * 2 + nh) * 1024;
    unsigned long long* ppub = pub + (size_t)(pid * 2 + (1 - nh)) * 1024;
    // reader coords: thread tid consumes partner u64s 2*tid, 2*tid+1
    int r_col = 128 * (1 - nh) + (tid >> 2);
    int r_row0 = (tid & 3) * 4;
    // writer coords
    int wr_p0 = (16 * w + l15) * 8 + 2 * lgp;

    // ---- preload xv for s=0 ----
    unsigned short xv_cur[16], xv_nxt[16];
    {
        int t0 = d ? 1023 : 0;
#pragma unroll
        for (int gt = 0; gt < 4; ++gt)
#pragma unroll
            for (int r = 0; r < 4; ++r) {
                int row = 16 * b + 4 * lgp + r;
                xv_cur[gt * 4 + r] = xgd[((size_t)row * 1024 + t0) * 1024 + 256 * gt + jg];
            }
    }
    __syncthreads();

    for (int s = 0; s < 1024; ++s) {
        int rp = (s + 1) & 1;     // parity holding h(s-1)
        int wp = s & 1;           // parity to write h(s)

        // A fragments: full h(s-1)
        bf8_t a[8];
#pragma unroll
        for (int ks = 0; ks < 8; ++ks)
            a[ks] = *reinterpret_cast<const bf8_t*>(&h_sh[rp][l15][32 * ks + 8 * lgp]);

        // prefetch next step's xg values (lands during compute + sync)
        {
            int sn = (s < 1023) ? (s + 1) : s;
            int tn = d ? (1023 - sn) : sn;
#pragma unroll
            for (int gt = 0; gt < 4; ++gt)
#pragma unroll
                for (int r = 0; r < 4; ++r) {
                    int row = 16 * b + 4 * lgp + r;
                    xv_nxt[gt * 4 + r] = xgd[((size_t)row * 1024 + tn) * 1024 + 256 * gt + jg];
                }
        }

        f4_t acc[4];
#pragma unroll
        for (int gt = 0; gt < 4; ++gt) { acc[gt][0] = 0.f; acc[gt][1] = 0.f; acc[gt][2] = 0.f; acc[gt][3] = 0.f; }
#pragma unroll
        for (int gt = 0; gt < 4; ++gt)
#pragma unroll
            for (int ks = 0; ks < 8; ++ks)
                acc[gt] = mfma16(a[ks], wreg[gt][ks], acc[gt]);

        // gates + state update
        unsigned short hbu[4];
#pragma unroll
        for (int r = 0; r < 4; ++r) {
            float iv = sigf(acc[0][r] + bf2f(xv_cur[0 + r]));
            float fv = sigf(acc[1][r] + bf2f(xv_cur[4 + r]));
            float gv = tanhf_(acc[2][r] + bf2f(xv_cur[8 + r]));
            float ov = sigf(acc[3][r] + bf2f(xv_cur[12 + r]));
            float cn = fv * c[r] + iv * gv;
            c[r] = cn;
            hbu[r] = f2bf(ov * tanhf_(cn));
        }

        // publish own half immediately (tag+data atomically per u64, one-way)
        {
            unsigned long long tg = ((unsigned long long)(unsigned)(s + 1)) << 32;
            unsigned long long u0 = (unsigned long long)hbu[0]
                                  | ((unsigned long long)hbu[1] << 16) | tg;
            unsigned long long u1 = (unsigned long long)hbu[2]
                                  | ((unsigned long long)hbu[3] << 16) | tg;
            __hip_atomic_store(&mypub[wr_p0], u0, __ATOMIC_RELAXED, __HIP_MEMORY_SCOPE_AGENT);
            __hip_atomic_store(&mypub[wr_p0 + 1], u1, __ATOMIC_RELAXED, __HIP_MEMORY_SCOPE_AGENT);
        }

        int t = d ? (1023 - s) : s;
        if (s < 1023) {
            // spin for partner's h(s) (tagged s+1), stage into partner half of h_sh[wp]
            unsigned tag = (unsigned)(s + 1);
            unsigned long long v0, v1;
            do {
                v0 = __hip_atomic_load(&ppub[2 * tid], __ATOMIC_RELAXED, __HIP_MEMORY_SCOPE_AGENT);
                v1 = __hip_atomic_load(&ppub[2 * tid + 1], __ATOMIC_RELAXED, __HIP_MEMORY_SCOPE_AGENT);
            } while ((unsigned)(v0 >> 32) != tag || (unsigned)(v1 >> 32) != tag);
            h_sh[wp][r_row0 + 0][r_col] = (unsigned short)v0;
            h_sh[wp][r_row0 + 1][r_col] = (unsigned short)(v0 >> 16);
            h_sh[wp][r_row0 + 2][r_col] = (unsigned short)v1;
            h_sh[wp][r_row0 + 3][r_col] = (unsigned short)(v1 >> 16);
        }

        // own h into LDS + global hs (off critical path)
#pragma unroll
        for (int r = 0; r < 4; ++r) {
            int m = 4 * lgp + r;
            h_sh[wp][m][jg] = hbu[r];
            hs[((size_t)(16 * b + m) * 1024 + t) * 512 + d * 256 + jg] = hbu[r];
        }

        // rotate xv double-buffer
#pragma unroll
        for (int k = 0; k < 16; ++k) xv_cur[k] = xv_nxt[k];

        __syncthreads();   // h_sh[wp] fully assembled for step s+1
    }
}

// ---------------- logits = hs @ Wout^T + b_out (N padded to 16) ----------------
__global__ __launch_bounds__(256) void logits_kernel(const unsigned short* hs,
        const unsigned short* wout_bf, const float* b_out, float* logits) {
    int w = threadIdx.x >> 6, l = threadIdx.x & 63, l15 = l & 15, lgp = l >> 4;
    int mt = blockIdx.x * 4 + w;         // 0..2047
    const unsigned short* arow = hs + (size_t)(16 * mt + l15) * 512 + 8 * lgp;
    const unsigned short* brow = wout_bf + (size_t)l15 * 512 + 8 * lgp;
    f4_t acc; acc[0] = 0.f; acc[1] = 0.f; acc[2] = 0.f; acc[3] = 0.f;
#pragma unroll
    for (int ks = 0; ks < 16; ++ks) {
        bf8_t a = *reinterpret_cast<const bf8_t*>(arow + 32 * ks);
        bf8_t b = *reinterpret_cast<const bf8_t*>(brow + 32 * ks);
        acc = mfma16(a, b, acc);
    }
    float bo = (l15 < NTAG) ? b_out[l15] : 0.0f;
#pragma unroll
    for (int r = 0; r < 4; ++r) {
        int bt = 16 * mt + 4 * lgp + r;
        logits[(size_t)bt * 16 + l15] = acc[r] + bo;
    }
}

// ---------------- Viterbi: one wave per sequence ----------------
__global__ __launch_bounds__(64) void viterbi_kernel(const float* logits, const float* crf,
                                                     float* out) {
    int b = blockIdx.x, j = threadIdx.x;
    __shared__ unsigned char bp[1024][16];
    __shared__ unsigned char pth[1024];
    float crfj[NTAG];
#pragma unroll
    for (int i = 0; i < NTAG; ++i)
        crfj[i] = (j < NTAG) ? crf[i * NTAG + j] : 0.0f;
    const float* lgt = logits + (size_t)b * 1024 * 16;
    float v = (j < NTAG) ? lgt[j] : -3.0e38f;
    for (int t = 1; t < 1024; ++t) {
        float lt = (j < NTAG) ? lgt[t * 16 + j] : 0.0f;
        float best = -3.0e38f; int arg = 0;
#pragma unroll
        for (int i = 0; i < NTAG; ++i) {
            float s = __shfl(v, i) + crfj[i];
            if (s > best) { best = s; arg = i; }   // strict > keeps lowest index (jnp.argmax)
        }
        v = (j < NTAG) ? (lt + best) : -3.0e38f;
        if (j < 16) bp[t][j] = (unsigned char)arg;
    }
    float best = -3.0e38f; int tag = 0;
#pragma unroll
    for (int jj = 0; jj < NTAG; ++jj) {
        float s = __shfl(v, jj);
        if (s > best) { best = s; tag = jj; }
    }
    __syncthreads();
    if (j == 0) {
        out[b] = best;
        int tg = tag;
        pth[1023] = (unsigned char)tg;
        for (int t = 1023; t >= 1; --t) {
            tg = bp[t][tg];
            pth[t - 1] = (unsigned char)tg;
        }
    }
    __syncthreads();
    float* pout = out + 32 + (size_t)b * 1024;
    for (int t = j; t < 1024; t += 64)
        pout[t] = (float)pth[t];
}

extern "C" void kernel_launch(void* const* d_in, const int* in_sizes, int n_in,
                              void* d_out, int out_size, void* d_ws, size_t ws_size,
                              hipStream_t stream) {
    const int* sent = (const int*)d_in[0];
    const float* emb = (const float*)d_in[1];
    const float* wih_f = (const float*)d_in[2];
    const float* whh_f = (const float*)d_in[3];
    const float* bih_f = (const float*)d_in[4];
    const float* bhh_f = (const float*)d_in[5];
    const float* wih_b = (const float*)d_in[6];
    const float* whh_b = (const float*)d_in[7];
    const float* bih_b = (const float*)d_in[8];
    const float* bhh_b = (const float*)d_in[9];
    const float* h0 = (const float*)d_in[10];
    const float* c0 = (const float*)d_in[11];
    const float* wout = (const float*)d_in[12];
    const float* b_out = (const float*)d_in[13];
    const float* crf = (const float*)d_in[14];

    char* ws = (char*)d_ws;
    unsigned short* whh_bf = (unsigned short*)(ws + 0);           // 1 MiB
    unsigned short* wih_bf = (unsigned short*)(ws + 1048576);     // 1 MiB
    float* biasc          = (float*)(ws + 2097152);               // 8 KiB
    unsigned short* wout_bf = (unsigned short*)(ws + 2105344);    // 16 KiB
    unsigned short* xbf   = (unsigned short*)(ws + 2121728);      // 16 MiB
    unsigned short* xg    = (unsigned short*)(ws + 18898944);     // 128 MiB
    unsigned short* hs    = (unsigned short*)(ws + 153116672);    // 32 MiB
    float* logits         = (float*)(ws + 186671104);             // 2 MiB
    // pub aliases the logits region (dead until logits_kernel, which runs after lstm)
    unsigned long long* pub = (unsigned long long*)(ws + 186671104);   // 64 KiB
    float* out = (float*)d_out;

    hipLaunchKernelGGL(prep_kernel, dim3(2152), dim3(256), 0, stream,
                       whh_f, whh_b, wih_f, wih_b, bih_f, bhh_f, bih_b, bhh_b, wout,
                       whh_bf, wih_bf, biasc, wout_bf, (unsigned int*)pub);
    hipLaunchKernelGGL(embed_kernel, dim3(8192), dim3(256), 0, stream, sent, emb, xbf);
    hipLaunchKernelGGL(xproj_kernel, dim3(2048, 8), dim3(256), 0, stream,
                       xbf, wih_bf, biasc, xg);
    hipLaunchKernelGGL(lstm_kernel, dim3(8), dim3(512), 0, stream,
                       xg, whh_bf, h0, c0, hs, pub);
    hipLaunchKernelGGL(logits_kernel, dim3(512), dim3(256), 0, stream,
                       hs, wout_bf, b_out, logits);
    hipLaunchKernelGGL(viterbi_kernel, dim3(32), dim3(64), 0, stream, logits, crf, out);
}